// Round 2
// 69.063 us; speedup vs baseline: 1.0109x; 1.0109x over previous
//
#include <hip/hip_runtime.h>

#define NB       128
#define M_TOTAL  8192
#define RESULT_FLOATS (M_TOTAL * 7)

typedef unsigned long long u64;
typedef unsigned int u32;

// One fused kernel. Grid = 256 blocks x 512 threads.
//   block b: tile tb = b>>2 (4 blocks per tile), sub = b&3.
//   Each block redundantly runs its tile's NMS and writes output for its
//   32 boxes (sub*32..+31).
// Global order key (tie-free, stable): aug = (sbits << 13) | (8191 - j),
// sbits = valid ? bits(score) : 0. rank_i = #{j : aug_j > aug_i}.
// Rank counting is register-blocked: 32 block-uniform box keys live in
// SGPRs (readfirstlane), per-thread keys stream from global.
// Work split: waves 0-6 count keys [0,8064) (18/thread); wave 7 runs the
// serial greedy NMS scan on lane 0 and then counts the 128 leftover keys —
// the scan hides under the counting on waves 0-6.
__global__ __launch_bounds__(512) void fused_nms_kernel(
    const float* __restrict__ tr,    // [8192][7]
    const int*   __restrict__ tp,    // [64][4]
    float*       __restrict__ out)   // [8192*7] rows + [8192] keep
{
    __shared__ u64   s_laug[NB];
    __shared__ float t_x1[NB], t_y1[NB], t_x2[NB], t_y2[NB], t_area[NB];
    __shared__ alignas(16) u32 sup32[NB][4];
    __shared__ u64   keepmask[2];
    __shared__ alignas(16) u32 s_wpart[8][16];   // packed u16 pairs per wave
    __shared__ int   s_p[NB];
    __shared__ float s_row[7][NB];               // clipped box + score/label/growth
    __shared__ int   s_nv[2];                    // per-wave valid counts

    const int tid = threadIdx.x;
    const int wv  = tid >> 6;
    const int sub = blockIdx.x & 3;
    const int tb  = blockIdx.x >> 2;
    const int g0  = tb * NB;

    // ---- score prefetch (issued first, long-latency) ----
    float sc[18];
    float sc2[2];
    int   j2 = 0;
    if (wv < 7) {
#pragma unroll
        for (int k = 0; k < 18; ++k)
            sc[k] = tr[(size_t)(tid + 448 * k) * 7 + 4];
    } else {
        j2 = 8064 + ((tid - 448) << 1);
        sc2[0] = tr[(size_t)j2 * 7 + 4];
        sc2[1] = tr[(size_t)(j2 + 1) * 7 + 4];
    }

    // ---- per-box NMS compute (threads 0..127) ----
    float sx1 = 0.f, sy1 = 0.f, sx2 = 0.f, sy2 = 0.f, area = 0.f;
    u64 aug_n = 0;
    bool valid = false;
    if (tid < NB) {
        const float* row = tr + (size_t)(g0 + tid) * 7;
        float x1 = row[0], y1 = row[1], x2 = row[2], y2 = row[3];
        float score = row[4], label = row[5], growth = row[6];
        float hf = (float)tp[tb * 4 + 0];
        float wf = (float)tp[tb * 4 + 2];
        float gx1 = fminf(fmaxf(__fadd_rn(x1, wf), 0.0f), 4096.0f);
        float gy1 = fminf(fmaxf(__fadd_rn(y1, hf), 0.0f), 4096.0f);
        float gx2 = fminf(fmaxf(__fadd_rn(x2, wf), 0.0f), 4096.0f);
        float gy2 = fminf(fmaxf(__fadd_rn(y2, hf), 0.0f), 4096.0f);
        s_row[0][tid] = gx1; s_row[1][tid] = gy1;
        s_row[2][tid] = gx2; s_row[3][tid] = gy2;
        s_row[4][tid] = score; s_row[5][tid] = label; s_row[6][tid] = growth;
        valid = score > 0.05f;
        u32 sb = valid ? __float_as_uint(score) : 0u;
        aug_n = ((u64)sb << 13) | (u64)(M_TOTAL - 1 - (g0 + tid));
        float c = __fmul_rn(label, 8192.0f);
        sx1 = __fadd_rn(gx1, c);
        sy1 = __fadd_rn(gy1, c);
        sx2 = __fadd_rn(gx2, c);
        sy2 = __fadd_rn(gy2, c);
        area = __fmul_rn(__fsub_rn(sx2, sx1), __fsub_rn(sy2, sy1));
        s_laug[tid] = aug_n;
        // validmask without LDS atomics: invalid boxes (sbits=0) sort after
        // ALL valid boxes, so valid ranks are exactly [0, Nvalid).
        u64 bm = __ballot(valid);
        if ((tid & 63) == 0) s_nv[tid >> 6] = (int)__popcll(bm);
    }
    __syncthreads();                                    // b1

    // ---- 32 block-uniform box keys -> SGPRs ----
    u64 bk[32];
#pragma unroll
    for (int b = 0; b < 32; ++b) {
        u64 v = s_laug[(sub << 5) + b];
        u32 lo = (u32)__builtin_amdgcn_readfirstlane((int)(u32)v);
        u32 hi = (u32)__builtin_amdgcn_readfirstlane((int)(u32)(v >> 32));
        bk[b] = ((u64)hi << 32) | (u64)lo;
    }

    // ---- local stable rank + scatter (threads 0..127) ----
    if (tid < NB) {
        int p = 0;
        const ulonglong2* lv = (const ulonglong2*)s_laug;
#pragma unroll 8
        for (int u = 0; u < 64; ++u) {
            ulonglong2 v = lv[u];
            p += (v.x > aug_n) + (v.y > aug_n);
        }
        t_x1[p] = sx1; t_y1[p] = sy1; t_x2[p] = sx2; t_y2[p] = sy2;
        t_area[p] = area;
        s_p[tid] = p;
    }
    __syncthreads();                                    // b2

    // ---- suppression bitmatrix: wave -> (row group rg, col quarter cq) ----
    // wave w: cq = w&3, rg = w>>2, row r = rg*64 + lane. Waves 4,5 cover
    // quarters entirely below the diagonal (w < r) -> all-zero, skipped.
    {
        const int cq = wv & 3;
        const int rg = wv >> 2;
        const int r  = (rg << 6) + (tid & 63);
        if (rg == 1 && cq < 2) {
            sup32[r][cq] = 0u;
        } else {
            const int wbase = cq * 32;
            float rx1 = t_x1[r], ry1 = t_y1[r], rx2 = t_x2[r], ry2 = t_y2[r];
            float ra = t_area[r];
            u32 m = 0, bnd = 0;
#pragma unroll 4
            for (int w2 = 0; w2 < 32; ++w2) {
                int w = wbase + w2;
                float ltx = fmaxf(rx1, t_x1[w]);
                float lty = fmaxf(ry1, t_y1[w]);
                float rbx = fminf(rx2, t_x2[w]);
                float rby = fminf(ry2, t_y2[w]);
                float iw = fmaxf(__fsub_rn(rbx, ltx), 0.0f);
                float ih = fmaxf(__fsub_rn(rby, lty), 0.0f);
                float inter = __fmul_rn(iw, ih);
                float uni   = __fsub_rn(__fadd_rn(ra, t_area[w]), inter);
                float denom = __fadd_rn(uni, 1e-8f);
                // iou > 0.5  <=>  inter > 0.5*denom (exact halving); sign of
                // the rounded diff is exact. Only |ratio-0.5| <~ 6e-8 can
                // disagree with __fdiv_rn; defer a 1e-6 window to exact div.
                float half = __fmul_rn(0.5f, denom);
                float diff = __fsub_rn(inter, half);
                bool gt = diff > 0.0f;
                m   |= ((u32)((w > r) && gt)) << w2;
                bnd |= ((u32)(fabsf(diff) <= __fmul_rn(denom, 1e-6f))) << w2;
            }
            if (__builtin_expect(bnd != 0u, 0)) {
                for (int w2 = 0; w2 < 32; ++w2) {
                    if ((bnd >> w2) & 1u) {
                        int w = wbase + w2;
                        float ltx = fmaxf(rx1, t_x1[w]);
                        float lty = fmaxf(ry1, t_y1[w]);
                        float rbx = fminf(rx2, t_x2[w]);
                        float rby = fminf(ry2, t_y2[w]);
                        float iw = fmaxf(__fsub_rn(rbx, ltx), 0.0f);
                        float ih = fmaxf(__fsub_rn(rby, lty), 0.0f);
                        float inter = __fmul_rn(iw, ih);
                        float uni   = __fsub_rn(__fadd_rn(ra, t_area[w]), inter);
                        float denom = __fadd_rn(uni, 1e-8f);
                        bool s = (w > r) && (__fdiv_rn(inter, denom) > 0.5f);
                        m = (m & ~(1u << w2)) | (((u32)s) << w2);
                    }
                }
            }
            sup32[r][cq] = m;
        }
    }
    __syncthreads();                                    // b3

    // ---- concurrent phase: waves 0-6 count; wave 7 scans then counts ----
    int cnt[32];
#pragma unroll
    for (int b = 0; b < 32; ++b) cnt[b] = 0;

    if (wv < 7) {
#pragma unroll
        for (int k = 0; k < 18; ++k) {
            int j = tid + 448 * k;
            u32 sb = (sc[k] > 0.05f) ? __float_as_uint(sc[k]) : 0u;
            u64 a = ((u64)sb << 13) | (u64)(M_TOTAL - 1 - j);
#pragma unroll
            for (int b = 0; b < 32; ++b) cnt[b] += (a > bk[b]);
        }
    } else {
        // serial greedy scan on lane 0 of wave 7 (hidden under counting)
        if (tid == 448) {
            int nv = s_nv[0] + s_nv[1];
            u64 v0 = (nv >= 64) ? ~0ull : ((1ull << nv) - 1ull);
            u64 v1 = (nv <= 64) ? 0ull
                   : ((nv >= 128) ? ~0ull : ((1ull << (nv - 64)) - 1ull));
            const ulonglong2* supv = (const ulonglong2*)sup32;
            u64 r0 = 0ull, r1 = 0ull;
            for (int c = 0; c < NB; c += 8) {
                ulonglong2 buf[8];
#pragma unroll
                for (int x = 0; x < 8; ++x) buf[x] = supv[c + x];
#pragma unroll
                for (int x = 0; x < 8; ++x) {
                    int q = c + x;
                    u64 alive = ((q < 64) ? ((v0 & ~r0) >> q)
                                          : ((v1 & ~r1) >> (q - 64))) & 1ull;
                    u64 take = 0ull - alive;
                    r0 |= buf[x].x & take;
                    r1 |= buf[x].y & take;
                }
            }
            keepmask[0] = v0 & ~r0;
            keepmask[1] = v1 & ~r1;
        }
        // leftover keys [8064, 8192): 2 per thread
#pragma unroll
        for (int k = 0; k < 2; ++k) {
            int j = j2 + k;
            float s = sc2[k];
            u32 sb = (s > 0.05f) ? __float_as_uint(s) : 0u;
            u64 a = ((u64)sb << 13) | (u64)(M_TOTAL - 1 - j);
#pragma unroll
            for (int b = 0; b < 32; ++b) cnt[b] += (a > bk[b]);
        }
    }

    // pack counter pairs (b, b+16) into u16 halves; totals <= 8191, no overflow
    u32 pk[16];
#pragma unroll
    for (int q = 0; q < 16; ++q)
        pk[q] = (u32)cnt[q] | ((u32)cnt[q + 16] << 16);

    // wave butterfly reduction (64 lanes)
#pragma unroll
    for (int q = 0; q < 16; ++q) {
        int c = (int)pk[q];
#pragma unroll
        for (int m = 1; m < 64; m <<= 1) c += __shfl_xor(c, m, 64);
        pk[q] = (u32)c;
    }
    {
        const int lane = tid & 63;
        if (lane == 0) {
            uint4* wp = (uint4*)&s_wpart[wv][0];
#pragma unroll
            for (int q4 = 0; q4 < 4; ++q4)
                wp[q4] = make_uint4(pk[4*q4], pk[4*q4+1], pk[4*q4+2], pk[4*q4+3]);
        }
    }
    __syncthreads();                                    // b4

    // ---- write this block's 32 boxes ----
    if (tid < 32) {
        int rank = 0;
        const int q = tid & 15;
        const int sh = (tid >> 4) << 4;
#pragma unroll
        for (int w = 0; w < 8; ++w)
            rank += (int)((s_wpart[w][q] >> sh) & 0xffffu);

        int nl = (sub << 5) + tid;       // local box in tile
        int pp = s_p[nl];
        float kf = ((keepmask[pp >> 6] >> (pp & 63)) & 1ull) ? 1.0f : 0.0f;

        float* o = out + (size_t)rank * 7;
        o[0] = __fmul_rn(s_row[0][nl], kf);
        o[1] = __fmul_rn(s_row[1][nl], kf);
        o[2] = __fmul_rn(s_row[2][nl], kf);
        o[3] = __fmul_rn(s_row[3][nl], kf);
        o[4] = __fmul_rn(s_row[4][nl], kf);
        o[5] = __fmul_rn(s_row[5][nl], kf);
        o[6] = __fmul_rn(s_row[6][nl], kf);
        out[RESULT_FLOATS + rank] = kf;
    }
}

extern "C" void kernel_launch(void* const* d_in, const int* in_sizes, int n_in,
                              void* d_out, int out_size, void* d_ws, size_t ws_size,
                              hipStream_t stream) {
    const float* tile_results   = (const float*)d_in[0];
    const int*   tile_positions = (const int*)d_in[1];
    float* out = (float*)d_out;

    hipLaunchKernelGGL(fused_nms_kernel, dim3(256), dim3(512), 0, stream,
                       tile_results, tile_positions, out);
}